// Round 6
// baseline (12596.107 us; speedup 1.0000x reference)
//
#include <hip/hip_runtime.h>

// SlotAttention: B=32, NF=16, N=192, D=256, S=21, 3 iters/frame.
// ROUND 6: fp32 I/O (per reference dtypes) + pure fp32 VALU skeleton (R5).
// No MFMA, no d_ws, one WG per batch. lnx cached in LDS as _Float16
// (col-major stride 193, conflict-free) -- everything else fp32.

typedef _Float16 f16;

__device__ inline float wredsum(float v) {
#pragma unroll
  for (int m = 32; m > 0; m >>= 1) v += __shfl_xor(v, m, 64);
  return v;
}
__device__ inline float fsigmoid(float x) { return 1.f / (1.f + __expf(-x)); }
__device__ inline float ftanh(float x) {
  float ax = fabsf(x);
  float e = __expf(-2.f * ax);
  return copysignf((1.f - e) / (1.f + e), x);
}

__global__ __launch_bounds__(512) void k_all(
    const float* __restrict__ x, const float* __restrict__ noise,
    const float* __restrict__ mu, const float* __restrict__ sigma,
    const float* __restrict__ Wq, const float* __restrict__ bq,
    const float* __restrict__ Wk, const float* __restrict__ bk,
    const float* __restrict__ Wv, const float* __restrict__ bv,
    const float* __restrict__ W1, const float* __restrict__ b1,
    const float* __restrict__ W2, const float* __restrict__ b2,
    const float* __restrict__ Wih, const float* __restrict__ bih,
    const float* __restrict__ Whh, const float* __restrict__ bhh,
    const float* __restrict__ g_in, const float* __restrict__ be_in,
    const float* __restrict__ g_sl, const float* __restrict__ be_sl,
    const float* __restrict__ g_ff, const float* __restrict__ be_ff,
    float* __restrict__ out_slots, float* __restrict__ out_attn) {
  __shared__ f16 LX[256 * 193];     // lnx column-major: LX[k*193 + j]   98,816 B
  __shared__ float SL[21 * 256];    // slots fp32                        21,504 B
  __shared__ float A[21 * 256];     // lnS / qk / P / h / ffa            21,504 B
  __shared__ float B[21 * 256];     // q / dots / attn / upd / lnH       21,504 B
  __shared__ float qb[21], rsum[21];

  const int b = blockIdx.x;
  const int tid = threadIdx.x;
  const int w = tid >> 6, lane = tid & 63;
  const int d = tid & 255;        // owned output column for streamed GEMMs
  const int half = tid >> 8;      // 0 or 1
  const int i0 = half * 11;       // rows 0..10 / 11..20
  const int ni = 11 - half;       // 11 / 10

  // ---- init slots: mu + sigma*noise ----
  for (int i = tid; i < 21 * 256; i += 512) {
    int s = i >> 8, dd = i & 255;
    SL[i] = mu[dd] + sigma[dd] * noise[((size_t)b * 21 + s) * 256 + dd];
  }
  __syncthreads();

  float hreg[11];
#pragma unroll
  for (int ii = 0; ii < 11; ii++) hreg[ii] = 0.f;

  for (int f = 0; f < 16; ++f) {
    const float* xf = x + ((size_t)(b * 16 + f)) * 192 * 256;
    // ---- frame LN -> LX (column-major, f16) ----
    for (int rr = 0; rr < 24; rr++) {
      int row = w + rr * 8;  // 0..191
      float4 xv = *(const float4*)(xf + row * 256 + lane * 4);
      float m = wredsum(xv.x + xv.y + xv.z + xv.w) * (1.f / 256.f);
      float d0 = xv.x - m, d1 = xv.y - m, d2 = xv.z - m, d3 = xv.w - m;
      float q2 = wredsum(d0 * d0 + d1 * d1 + d2 * d2 + d3 * d3);
      float rs = 1.f / sqrtf(q2 * (1.f / 256.f) + 1e-5f);
      int c = lane * 4;
      LX[(c + 0) * 193 + row] = (f16)(d0 * rs * g_in[c + 0] + be_in[c + 0]);
      LX[(c + 1) * 193 + row] = (f16)(d1 * rs * g_in[c + 1] + be_in[c + 1]);
      LX[(c + 2) * 193 + row] = (f16)(d2 * rs * g_in[c + 2] + be_in[c + 2]);
      LX[(c + 3) * 193 + row] = (f16)(d3 * rs * g_in[c + 3] + be_in[c + 3]);
    }
    __syncthreads();

    for (int it = 0; it < 3; ++it) {
      // ---- P1: lnS = LN(SL) -> A ----
#pragma unroll
      for (int rr = 0; rr < 3; rr++) {
        int row = w + rr * 8;
        if (row < 21) {
          float4 xv = *(const float4*)(SL + row * 256 + lane * 4);
          float m = wredsum(xv.x + xv.y + xv.z + xv.w) * (1.f / 256.f);
          float d0 = xv.x - m, d1 = xv.y - m, d2 = xv.z - m, d3 = xv.w - m;
          float q2 = wredsum(d0 * d0 + d1 * d1 + d2 * d2 + d3 * d3);
          float rs = 1.f / sqrtf(q2 * (1.f / 256.f) + 1e-5f);
          int c = lane * 4;
          A[row * 256 + c + 0] = d0 * rs * g_sl[c + 0] + be_sl[c + 0];
          A[row * 256 + c + 1] = d1 * rs * g_sl[c + 1] + be_sl[c + 1];
          A[row * 256 + c + 2] = d2 * rs * g_sl[c + 2] + be_sl[c + 2];
          A[row * 256 + c + 3] = d3 * rs * g_sl[c + 3] + be_sl[c + 3];
        }
      }
      __syncthreads();
      // ---- P2: q = lnS @ Wq^T + bq -> B ----
      {
        float acc[11];
#pragma unroll
        for (int ii = 0; ii < 11; ii++) acc[ii] = 0.f;
        for (int k = 0; k < 256; k += 4) {
          float4 w4 = *(const float4*)(Wq + (size_t)d * 256 + k);
#pragma unroll
          for (int ii = 0; ii < 11; ii++)
            if (ii < ni) {
              float4 av = *(const float4*)(A + (i0 + ii) * 256 + k);
              acc[ii] += av.x * w4.x + av.y * w4.y + av.z * w4.z + av.w * w4.w;
            }
        }
        float bb = bq[d];
#pragma unroll
        for (int ii = 0; ii < 11; ii++)
          if (ii < ni) B[(i0 + ii) * 256 + d] = acc[ii] + bb;
      }
      __syncthreads();
      // ---- P3: qk = q @ Wk (over d) -> A ; qb[i] = q[i]·bk ----
      {
        float acc[11];
#pragma unroll
        for (int ii = 0; ii < 11; ii++) acc[ii] = 0.f;
        for (int dd = 0; dd < 256; dd += 4) {
          float w0 = Wk[(size_t)(dd + 0) * 256 + d];
          float w1 = Wk[(size_t)(dd + 1) * 256 + d];
          float w2 = Wk[(size_t)(dd + 2) * 256 + d];
          float w3 = Wk[(size_t)(dd + 3) * 256 + d];
#pragma unroll
          for (int ii = 0; ii < 11; ii++)
            if (ii < ni) {
              float4 qv = *(const float4*)(B + (i0 + ii) * 256 + dd);
              acc[ii] += qv.x * w0 + qv.y * w1 + qv.z * w2 + qv.w * w3;
            }
        }
#pragma unroll
        for (int ii = 0; ii < 11; ii++)
          if (ii < ni) A[(i0 + ii) * 256 + d] = acc[ii];
        if (tid < 21) {
          float s = 0.f;
          for (int dd = 0; dd < 256; dd++) s += B[tid * 256 + dd] * bk[dd];
          qb[tid] = s;
        }
      }
      __syncthreads();
      // ---- P4: dots = (qk·lnx^T + qb)*scale -> B ----
      for (int c = 0; c < 8; c++) {
        int o = tid + (c << 9);
        if (o < 4032) {
          int i = o / 192, j = o - i * 192;
          float s = 0.f;
          for (int k = 0; k < 256; k += 4) {
            float4 q4 = *(const float4*)(A + i * 256 + k);
            s += q4.x * (float)LX[(k + 0) * 193 + j];
            s += q4.y * (float)LX[(k + 1) * 193 + j];
            s += q4.z * (float)LX[(k + 2) * 193 + j];
            s += q4.w * (float)LX[(k + 3) * 193 + j];
          }
          B[i * 256 + j] = (s + qb[i]) * 0.0625f;
        }
      }
      __syncthreads();
      // ---- P5a: softmax over slots per column + EPS ----
      if (tid < 192) {
        int j = tid;
        float mx = -1e30f;
#pragma unroll
        for (int i = 0; i < 21; i++) mx = fmaxf(mx, B[i * 256 + j]);
        float e[21], sum = 0.f;
#pragma unroll
        for (int i = 0; i < 21; i++) { e[i] = __expf(B[i * 256 + j] - mx); sum += e[i]; }
        float inv = 1.f / sum;
#pragma unroll
        for (int i = 0; i < 21; i++) B[i * 256 + j] = e[i] * inv + 1e-8f;
      }
      __syncthreads();
      // ---- P5b: row sums over N ----
#pragma unroll
      for (int q3 = 0; q3 < 3; q3++) {
        int i = w * 3 + q3;
        if (i < 21) {
          float s = B[i * 256 + lane] + B[i * 256 + lane + 64] + B[i * 256 + lane + 128];
          s = wredsum(s);
          if (lane == 0) rsum[i] = s;
        }
      }
      __syncthreads();
      // ---- P5c: attn = ao/rsum in B ; emit attn_ori on it==2 ----
      {
        float* oa = out_attn + ((size_t)(b * 16 + f)) * 4032;
        for (int idx = tid; idx < 4032; idx += 512) {
          int i = idx / 192, j = idx - i * 192;
          float ao = B[i * 256 + j];
          if (it == 2) oa[idx] = ao;
          B[i * 256 + j] = ao / rsum[i];
        }
      }
      __syncthreads();
      // ---- P6: P = attn @ lnx -> A  (reduce over j=192) ----
      {
        float acc[11];
#pragma unroll
        for (int ii = 0; ii < 11; ii++) acc[ii] = 0.f;
        for (int j = 0; j < 192; j += 4) {
          float l0 = (float)LX[d * 193 + j + 0];
          float l1 = (float)LX[d * 193 + j + 1];
          float l2 = (float)LX[d * 193 + j + 2];
          float l3 = (float)LX[d * 193 + j + 3];
#pragma unroll
          for (int ii = 0; ii < 11; ii++)
            if (ii < ni) {
              float4 at = *(const float4*)(B + (i0 + ii) * 256 + j);
              acc[ii] += at.x * l0 + at.y * l1 + at.z * l2 + at.w * l3;
            }
        }
#pragma unroll
        for (int ii = 0; ii < 11; ii++)
          if (ii < ni) A[(i0 + ii) * 256 + d] = acc[ii];
      }
      __syncthreads();
      // ---- P7: upd = P @ Wv^T + bv -> B ----
      {
        float acc[11];
#pragma unroll
        for (int ii = 0; ii < 11; ii++) acc[ii] = 0.f;
        for (int k = 0; k < 256; k += 4) {
          float4 w4 = *(const float4*)(Wv + (size_t)d * 256 + k);
#pragma unroll
          for (int ii = 0; ii < 11; ii++)
            if (ii < ni) {
              float4 pv = *(const float4*)(A + (i0 + ii) * 256 + k);
              acc[ii] += pv.x * w4.x + pv.y * w4.y + pv.z * w4.z + pv.w * w4.w;
            }
        }
        float bb = bv[d];
#pragma unroll
        for (int ii = 0; ii < 11; ii++)
          if (ii < ni) B[(i0 + ii) * 256 + d] = acc[ii] + bb;
      }
      __syncthreads();
      // ---- P8: GRU(upd=B, slots=SL) -> hreg, A := h ----
      {
        float aR[11], aZ[11], aNi[11], aNh[11];
#pragma unroll
        for (int ii = 0; ii < 11; ii++) { aR[ii] = 0.f; aZ[ii] = 0.f; aNi[ii] = 0.f; aNh[ii] = 0.f; }
        for (int k = 0; k < 256; k += 4) {
          float4 wr4 = *(const float4*)(Wih + (size_t)d * 256 + k);
          float4 wz4 = *(const float4*)(Wih + (size_t)(256 + d) * 256 + k);
          float4 wn4 = *(const float4*)(Wih + (size_t)(512 + d) * 256 + k);
          float4 vr4 = *(const float4*)(Whh + (size_t)d * 256 + k);
          float4 vz4 = *(const float4*)(Whh + (size_t)(256 + d) * 256 + k);
          float4 vn4 = *(const float4*)(Whh + (size_t)(512 + d) * 256 + k);
#pragma unroll
          for (int ii = 0; ii < 11; ii++)
            if (ii < ni) {
              float4 u4 = *(const float4*)(B + (i0 + ii) * 256 + k);
              float4 s4 = *(const float4*)(SL + (i0 + ii) * 256 + k);
              aR[ii] += u4.x * wr4.x + u4.y * wr4.y + u4.z * wr4.z + u4.w * wr4.w
                      + s4.x * vr4.x + s4.y * vr4.y + s4.z * vr4.z + s4.w * vr4.w;
              aZ[ii] += u4.x * wz4.x + u4.y * wz4.y + u4.z * wz4.z + u4.w * wz4.w
                      + s4.x * vz4.x + s4.y * vz4.y + s4.z * vz4.z + s4.w * vz4.w;
              aNi[ii] += u4.x * wn4.x + u4.y * wn4.y + u4.z * wn4.z + u4.w * wn4.w;
              aNh[ii] += s4.x * vn4.x + s4.y * vn4.y + s4.z * vn4.z + s4.w * vn4.w;
            }
        }
        float bir = bih[d], biz = bih[256 + d], bin = bih[512 + d];
        float bhr = bhh[d], bhz = bhh[256 + d], bhn = bhh[512 + d];
#pragma unroll
        for (int ii = 0; ii < 11; ii++)
          if (ii < ni) {
            float r = fsigmoid(aR[ii] + bir + bhr);
            float z = fsigmoid(aZ[ii] + biz + bhz);
            float n = ftanh(aNi[ii] + bin + r * (aNh[ii] + bhn));
            float h = (1.f - z) * n + z * SL[(i0 + ii) * 256 + d];
            hreg[ii] = h;
            A[(i0 + ii) * 256 + d] = h;
          }
      }
      __syncthreads();
      // ---- P9: lnH = LN(A) -> B ----
#pragma unroll
      for (int rr = 0; rr < 3; rr++) {
        int row = w + rr * 8;
        if (row < 21) {
          float4 xv = *(const float4*)(A + row * 256 + lane * 4);
          float m = wredsum(xv.x + xv.y + xv.z + xv.w) * (1.f / 256.f);
          float d0 = xv.x - m, d1 = xv.y - m, d2 = xv.z - m, d3 = xv.w - m;
          float q2 = wredsum(d0 * d0 + d1 * d1 + d2 * d2 + d3 * d3);
          float rs = 1.f / sqrtf(q2 * (1.f / 256.f) + 1e-5f);
          int c = lane * 4;
          B[row * 256 + c + 0] = d0 * rs * g_ff[c + 0] + be_ff[c + 0];
          B[row * 256 + c + 1] = d1 * rs * g_ff[c + 1] + be_ff[c + 1];
          B[row * 256 + c + 2] = d2 * rs * g_ff[c + 2] + be_ff[c + 2];
          B[row * 256 + c + 3] = d3 * rs * g_ff[c + 3] + be_ff[c + 3];
        }
      }
      __syncthreads();
      // ---- P10: ffa = relu(lnH @ W1^T + b1) -> A ----
      {
        float acc[11];
#pragma unroll
        for (int ii = 0; ii < 11; ii++) acc[ii] = 0.f;
        for (int k = 0; k < 256; k += 4) {
          float4 w4 = *(const float4*)(W1 + (size_t)d * 256 + k);
#pragma unroll
          for (int ii = 0; ii < 11; ii++)
            if (ii < ni) {
              float4 lv = *(const float4*)(B + (i0 + ii) * 256 + k);
              acc[ii] += lv.x * w4.x + lv.y * w4.y + lv.z * w4.z + lv.w * w4.w;
            }
        }
        float bb = b1[d];
#pragma unroll
        for (int ii = 0; ii < 11; ii++)
          if (ii < ni) A[(i0 + ii) * 256 + d] = fmaxf(acc[ii] + bb, 0.f);
      }
      __syncthreads();
      // ---- P11: SL = h + ffa @ W2^T + b2 ----
      {
        float acc[11];
#pragma unroll
        for (int ii = 0; ii < 11; ii++) acc[ii] = 0.f;
        for (int k = 0; k < 256; k += 4) {
          float4 w4 = *(const float4*)(W2 + (size_t)d * 256 + k);
#pragma unroll
          for (int ii = 0; ii < 11; ii++)
            if (ii < ni) {
              float4 fv = *(const float4*)(A + (i0 + ii) * 256 + k);
              acc[ii] += fv.x * w4.x + fv.y * w4.y + fv.z * w4.z + fv.w * w4.w;
            }
        }
        float bb = b2[d];
#pragma unroll
        for (int ii = 0; ii < 11; ii++)
          if (ii < ni) SL[(i0 + ii) * 256 + d] = hreg[ii] + acc[ii] + bb;
      }
      __syncthreads();
    }
  }
  // ---- output: slots[:, :20, :] ----
  for (int i = tid; i < 20 * 256; i += 512) {
    int s = i >> 8, dd = i & 255;
    out_slots[((size_t)b * 20 + s) * 256 + dd] = SL[s * 256 + dd];
  }
}

extern "C" void kernel_launch(void* const* d_in, const int* in_sizes, int n_in,
                              void* d_out, int out_size, void* d_ws, size_t ws_size,
                              hipStream_t stream) {
  const float* inputs = (const float*)d_in[0];
  const float* noise = (const float*)d_in[1];
  const float* mu = (const float*)d_in[2];
  const float* sigma = (const float*)d_in[3];
  const float* Wq = (const float*)d_in[4];
  const float* bq = (const float*)d_in[5];
  const float* Wk = (const float*)d_in[6];
  const float* bk = (const float*)d_in[7];
  const float* Wv = (const float*)d_in[8];
  const float* bv = (const float*)d_in[9];
  const float* W1 = (const float*)d_in[10];
  const float* b1 = (const float*)d_in[11];
  const float* W2 = (const float*)d_in[12];
  const float* b2 = (const float*)d_in[13];
  const float* Wih = (const float*)d_in[14];
  const float* bih = (const float*)d_in[15];
  const float* Whh = (const float*)d_in[16];
  const float* bhh = (const float*)d_in[17];
  const float* g_in = (const float*)d_in[18];
  const float* be_in = (const float*)d_in[19];
  const float* g_sl = (const float*)d_in[20];
  const float* be_sl = (const float*)d_in[21];
  const float* g_ff = (const float*)d_in[22];
  const float* be_ff = (const float*)d_in[23];

  float* out_slots = (float*)d_out;
  float* out_attn = out_slots + 32 * 20 * 256;

  k_all<<<32, 512, 0, stream>>>(inputs, noise, mu, sigma, Wq, bq, Wk, bk, Wv, bv,
                                W1, b1, W2, b2, Wih, bih, Whh, bhh,
                                g_in, be_in, g_sl, be_sl, g_ff, be_ff,
                                out_slots, out_attn);
}